// Round 2
// baseline (4465.044 us; speedup 1.0000x reference)
//
#include <hip/hip_runtime.h>
#include <hip/hip_bf16.h>

typedef unsigned short u16;

#define B_  4
#define S_  4096
#define D_  1024
#define A_  1024
#define FF_ 4096
#define NB  4
#define LN_EPS 1e-6f

typedef __bf16 bf16x8 __attribute__((ext_vector_type(8)));
typedef float  floatx4 __attribute__((ext_vector_type(4)));

__device__ __forceinline__ float gelu_f(float x) {
    // jax.nn.gelu approximate=True (tanh form)
    float x3 = x * x * x;
    return 0.5f * x * (1.0f + tanhf(0.7978845608028654f * (x + 0.044715f * x3)));
}

__device__ __forceinline__ u16 f2bf(float f) {
    __bf16 h = (__bf16)f;   // RNE convert
    return *(u16*)&h;
}

__device__ __forceinline__ float bf2f(u16 u) {
    unsigned int v = ((unsigned int)u) << 16;
    float f;
    __builtin_memcpy(&f, &v, 4);
    return f;
}

// ---------------- zero the KV/Ksum accumulators ------------------------------
__global__ __launch_bounds__(256) void zero_kv(float* __restrict__ p) {
    int idx = (blockIdx.x * 256 + threadIdx.x) * 4;   // 8 blocks -> 8192 floats
    *(float4*)(p + idx) = (float4){0.f, 0.f, 0.f, 0.f};
}

// ---------------- weight transpose + downcast: W[K,N] f32 -> Wt[N,K] bf16 ----
__global__ __launch_bounds__(256) void transpose_w(const float* __restrict__ W,
                                                   u16* __restrict__ Wt,
                                                   int K, int N) {
    __shared__ float tile[32][33];
    int tx = threadIdx.x;         // 0..31
    int ty = threadIdx.y;         // 0..7
    int n0 = blockIdx.x * 32;
    int k0 = blockIdx.y * 32;
#pragma unroll
    for (int r = 0; r < 4; r++) {
        int k = k0 + ty + r * 8;
        tile[ty + r * 8][tx] = W[(size_t)k * N + n0 + tx];
    }
    __syncthreads();
#pragma unroll
    for (int r = 0; r < 4; r++) {
        int n = n0 + ty + r * 8;
        Wt[(size_t)n * K + k0 + tx] = f2bf(tile[tx][ty + r * 8]);
    }
}

// ---------------- bf16 MFMA GEMM: C[M,N] = A[M,K] * Bt[N,K]^T + bias --------
// MODE: 0 = elu+1, 1 = identity, 2 = gelu(gelu()), 3 = gelu   (all -> bf16)
template <int MODE>
__global__ __launch_bounds__(256) void gemm_bt(const u16* __restrict__ Amat,
                                               const u16* __restrict__ Bt,
                                               const float* __restrict__ bias,
                                               u16* __restrict__ out,
                                               int M, int N, int K) {
    // 128x128 tile, BK=32, 4 waves each computing 64x64 via 4x4 MFMA 16x16x32
    __shared__ u16 As[128 * 40];   // +8 shorts pad: 2-way bank alias only (free)
    __shared__ u16 Bs[128 * 40];

    const int t    = threadIdx.x;
    const int m0   = blockIdx.y * 128;
    const int n0   = blockIdx.x * 128;
    const int wave = t >> 6;
    const int lane = t & 63;
    const int wm   = (wave & 1) * 64;
    const int wn   = (wave >> 1) * 64;
    const int lm   = lane & 15;
    const int quad = lane >> 4;

    floatx4 acc[4][4];
#pragma unroll
    for (int i = 0; i < 4; i++)
#pragma unroll
        for (int j = 0; j < 4; j++) acc[i][j] = (floatx4){0.f, 0.f, 0.f, 0.f};

    for (int k0 = 0; k0 < K; k0 += 32) {
        __syncthreads();
#pragma unroll
        for (int p = 0; p < 2; p++) {
            int e   = p * 256 + t;        // 0..511 16B-chunks (8 shorts each)
            int row = e >> 2;
            int c8  = (e & 3) * 8;
            uint4 va = *(const uint4*)(Amat + (size_t)(m0 + row) * K + k0 + c8);
            *(uint4*)&As[row * 40 + c8] = va;
            uint4 vb = *(const uint4*)(Bt + (size_t)(n0 + row) * K + k0 + c8);
            *(uint4*)&Bs[row * 40 + c8] = vb;
        }
        __syncthreads();

        bf16x8 af[4], bf[4];
#pragma unroll
        for (int i = 0; i < 4; i++)
            af[i] = *(const bf16x8*)&As[(wm + i * 16 + lm) * 40 + quad * 8];
#pragma unroll
        for (int j = 0; j < 4; j++)
            bf[j] = *(const bf16x8*)&Bs[(wn + j * 16 + lm) * 40 + quad * 8];

#pragma unroll
        for (int i = 0; i < 4; i++)
#pragma unroll
            for (int j = 0; j < 4; j++)
                acc[i][j] = __builtin_amdgcn_mfma_f32_16x16x32_bf16(af[i], bf[j], acc[i][j], 0, 0, 0);
    }

    // epilogue: D row = quad*4 + reg (within 16), col = lane&15
#pragma unroll
    for (int j = 0; j < 4; j++) {
        int col  = n0 + wn + j * 16 + lm;
        float bv = bias[col];
#pragma unroll
        for (int i = 0; i < 4; i++) {
            int rbase = m0 + wm + i * 16 + quad * 4;
#pragma unroll
            for (int r = 0; r < 4; r++) {
                float z = acc[i][j][r] + bv;
                float o;
                if (MODE == 0)      o = (z > 0.f) ? (z + 1.f) : __expf(z);
                else if (MODE == 1) o = z;
                else if (MODE == 2) o = gelu_f(gelu_f(z));
                else                o = gelu_f(z);
                out[(size_t)(rbase + r) * N + col] = f2bf(o);
            }
        }
    }
}

// ---------------- KV / Ksum reduction over S ---------------------------------
__global__ __launch_bounds__(256) void kv_reduce(const u16* __restrict__ Kb,
                                                 const u16* __restrict__ vb,
                                                 float* __restrict__ KV,
                                                 float* __restrict__ Ks) {
    int n  = blockIdx.z;
    int h  = blockIdx.x * 256 + threadIdx.x;
    int s0 = blockIdx.y * 128;
    const u16* kp = Kb + (size_t)n * S_ * A_ + (size_t)s0 * A_ + h;
    const u16* vp = vb + (size_t)n * S_ * A_ + (size_t)s0 * A_ + h;
    float kv = 0.f, ks = 0.f;
#pragma unroll 4
    for (int s = 0; s < 128; s++) {
        float k = bf2f(kp[(size_t)s * A_]);
        float v = bf2f(vp[(size_t)s * A_]);
        kv += k * v;
        ks += k;
    }
    atomicAdd(&KV[n * A_ + h], kv);
    atomicAdd(&Ks[n * A_ + h], ks);
}

// ---------------- elementwise linear-attention output ------------------------
__global__ __launch_bounds__(256) void linattn_ew(const u16* __restrict__ Qb,
                                                  const float* __restrict__ KV,
                                                  const float* __restrict__ Ks,
                                                  u16* __restrict__ vout) {
    size_t idx = ((size_t)blockIdx.x * 256 + threadIdx.x) * 4;
    int n = (int)(idx >> 22);          // S_*A_ = 2^22
    int h = (int)(idx & (A_ - 1));
    ushort4 q4 = *(const ushort4*)(Qb + idx);
    int base = n * A_ + h;
    float q0 = bf2f(q4.x), q1 = bf2f(q4.y), q2 = bf2f(q4.z), q3 = bf2f(q4.w);
    float o0 = q0 * KV[base + 0] / (q0 * Ks[base + 0] + 1e-6f);
    float o1 = q1 * KV[base + 1] / (q1 * Ks[base + 1] + 1e-6f);
    float o2 = q2 * KV[base + 2] / (q2 * Ks[base + 2] + 1e-6f);
    float o3 = q3 * KV[base + 3] / (q3 * Ks[base + 3] + 1e-6f);
    ushort4 o;
    o.x = f2bf(o0); o.y = f2bf(o1); o.z = f2bf(o2); o.w = f2bf(o3);
    *(ushort4*)(vout + idx) = o;
}

// ---------------- x init: f32 copy (residual) + bf16 cast --------------------
__global__ __launch_bounds__(256) void convert_x(const float* __restrict__ x,
                                                 float* __restrict__ xf,
                                                 u16* __restrict__ xb) {
    size_t idx = ((size_t)blockIdx.x * 256 + threadIdx.x) * 4;
    float4 v = *(const float4*)(x + idx);
    *(float4*)(xf + idx) = v;
    ushort4 o;
    o.x = f2bf(v.x); o.y = f2bf(v.y); o.z = f2bf(v.z); o.w = f2bf(v.w);
    *(ushort4*)(xb + idx) = o;
}

// ---------------- fused residual + LayerNorm (y in bf16, residual fp32) ------
__global__ __launch_bounds__(256) void ln_fused(const u16* __restrict__ y,
                                                const float* __restrict__ res,
                                                const float* __restrict__ sc,
                                                const float* __restrict__ bs,
                                                float* __restrict__ xf,
                                                u16* __restrict__ xb) {
    __shared__ float red[256];
    int row = blockIdx.x;
    int t   = threadIdx.x;
    const u16* yp   = y + (size_t)row * D_;
    const float* rp = res + (size_t)row * D_;
    float v[4];
    float lsum = 0.f;
#pragma unroll
    for (int i = 0; i < 4; i++) {
        int j = t + i * 256;
        v[i] = bf2f(yp[j]) + rp[j];
        lsum += v[i];
    }
    red[t] = lsum;
    __syncthreads();
    for (int s = 128; s > 0; s >>= 1) {
        if (t < s) red[t] += red[t + s];
        __syncthreads();
    }
    float mean = red[0] * (1.0f / D_);
    __syncthreads();
    float lvar = 0.f;
#pragma unroll
    for (int i = 0; i < 4; i++) {
        float d = v[i] - mean;
        lvar += d * d;
    }
    red[t] = lvar;
    __syncthreads();
    for (int s = 128; s > 0; s >>= 1) {
        if (t < s) red[t] += red[t + s];
        __syncthreads();
    }
    float rstd = rsqrtf(red[0] * (1.0f / D_) + LN_EPS);
#pragma unroll
    for (int i = 0; i < 4; i++) {
        int j = t + i * 256;
        float o = (v[i] - mean) * rstd * sc[j] + bs[j];
        xf[(size_t)row * D_ + j] = o;
        xb[(size_t)row * D_ + j] = f2bf(o);
    }
}

extern "C" void kernel_launch(void* const* d_in, const int* in_sizes, int n_in,
                              void* d_out, int out_size, void* d_ws, size_t ws_size,
                              hipStream_t stream) {
    const float* x_in = (const float*)d_in[0];
    const float* Wq   = (const float*)d_in[1];
    const float* bq   = (const float*)d_in[2];
    const float* Wk   = (const float*)d_in[3];
    const float* bk   = (const float*)d_in[4];
    const float* Wv   = (const float*)d_in[5];
    const float* bv   = (const float*)d_in[6];
    const float* Wo   = (const float*)d_in[7];
    const float* bo   = (const float*)d_in[8];
    const float* ln1s = (const float*)d_in[9];
    const float* ln1b = (const float*)d_in[10];
    const float* W1   = (const float*)d_in[11];
    const float* b1   = (const float*)d_in[12];
    const float* W2   = (const float*)d_in[13];
    const float* b2   = (const float*)d_in[14];
    const float* ln2s = (const float*)d_in[15];
    const float* ln2b = (const float*)d_in[16];

    const size_t MB = 1024 * 1024;
    char* ws = (char*)d_ws;
    // Workspace layout: 176 MB total (well under input footprint ~256 MB).
    // d_out itself doubles as the fp32 residual stream (xf).
    float* xf  = (float*)d_out;              // 64 MB  fp32 residual / final out
    u16*   xb  = (u16*)(ws);                 // 32 MB  bf16 x (GEMM A)
    u16*   yb  = (u16*)(ws + 32 * MB);       // 32 MB  bf16 GEMM out: v / a / f
    u16*   Qb  = (u16*)(ws + 64 * MB);       // 32 MB  bf16 Q
    u16*   Kb  = (u16*)(ws + 96 * MB);       // 32 MB  bf16 K, then Vattn
    u16*   hcb = (u16*)(ws + 128 * MB);      // 32 MB  bf16 FF hidden (4096-row chunk)
    u16*   Wt1 = (u16*)(ws + 160 * MB);      // 8 MB   bf16 transposed weight
    u16*   Wt2 = (u16*)(ws + 168 * MB);      // 8 MB   bf16 transposed weight (W2)
    float* kvb = (float*)(ws + 128 * MB);    // 32 KB  KV+Ksum (overlays hcb; disjoint in time)
    float* KV  = kvb;
    float* Ks  = kvb + B_ * A_;

    const int M = B_ * S_;   // 16384
    const int MC = 4096;     // FF row chunk

    convert_x<<<dim3(M * D_ / 1024), 256, 0, stream>>>(x_in, xf, xb);

    for (int i = 0; i < NB; i++) {
        const float* Wq_i = Wq + (size_t)i * D_ * A_;
        const float* Wk_i = Wk + (size_t)i * D_ * A_;
        const float* Wv_i = Wv + (size_t)i * D_ * A_;
        const float* Wo_i = Wo + (size_t)i * A_ * D_;
        const float* W1_i = W1 + (size_t)i * D_ * FF_;
        const float* W2_i = W2 + (size_t)i * FF_ * D_;

        // Q = elu(x@Wq + bq) + 1
        transpose_w<<<dim3(A_ / 32, D_ / 32), dim3(32, 8), 0, stream>>>(Wq_i, Wt1, D_, A_);
        gemm_bt<0><<<dim3(A_ / 128, M / 128), 256, 0, stream>>>(xb, Wt1, bq + i * A_, Qb, M, A_, D_);
        // K = elu(x@Wk + bk) + 1
        transpose_w<<<dim3(A_ / 32, D_ / 32), dim3(32, 8), 0, stream>>>(Wk_i, Wt1, D_, A_);
        gemm_bt<0><<<dim3(A_ / 128, M / 128), 256, 0, stream>>>(xb, Wt1, bk + i * A_, Kb, M, A_, D_);
        // v = x@Wv + bv
        transpose_w<<<dim3(A_ / 32, D_ / 32), dim3(32, 8), 0, stream>>>(Wv_i, Wt1, D_, A_);
        gemm_bt<1><<<dim3(A_ / 128, M / 128), 256, 0, stream>>>(xb, Wt1, bv + i * A_, yb, M, A_, D_);

        // KV[n,h] = sum_s K*v ; Ksum[n,h] = sum_s K
        zero_kv<<<dim3(8), 256, 0, stream>>>(kvb);
        kv_reduce<<<dim3(A_ / 256, S_ / 128, B_), 256, 0, stream>>>(Kb, yb, KV, Ks);

        // Vattn = Q*KV / (Q*Ksum + 1e-6)  (overwrites Kb)
        linattn_ew<<<dim3(M * A_ / 1024), 256, 0, stream>>>(Qb, KV, Ks, Kb);

        // a = gelu(gelu(Vattn@Wo + bo))
        transpose_w<<<dim3(D_ / 32, A_ / 32), dim3(32, 8), 0, stream>>>(Wo_i, Wt1, A_, D_);
        gemm_bt<2><<<dim3(D_ / 128, M / 128), 256, 0, stream>>>(Kb, Wt1, bo + i * D_, yb, M, D_, A_);

        // x = LN(a + residual)
        ln_fused<<<dim3(M), 256, 0, stream>>>(yb, xf, ln1s + i * D_, ln1b + i * D_, xf, xb);

        // FF, chunked over rows to keep the hidden buffer at 32 MB
        transpose_w<<<dim3(FF_ / 32, D_ / 32), dim3(32, 8), 0, stream>>>(W1_i, Wt1, D_, FF_);
        transpose_w<<<dim3(D_ / 32, FF_ / 32), dim3(32, 8), 0, stream>>>(W2_i, Wt2, FF_, D_);
        for (int c = 0; c < M / MC; c++) {
            const u16* xbc = xb + (size_t)c * MC * D_;
            u16*       ybc = yb + (size_t)c * MC * D_;
            // h = gelu(x@W1 + b1)
            gemm_bt<3><<<dim3(FF_ / 128, MC / 128), 256, 0, stream>>>(xbc, Wt1, b1 + i * FF_, hcb, MC, FF_, D_);
            // f = gelu(h@W2 + b2)
            gemm_bt<3><<<dim3(D_ / 128, MC / 128), 256, 0, stream>>>(hcb, Wt2, b2 + i * D_, ybc, MC, D_, FF_);
        }

        // x = LN(f + residual)  (final block writes d_out via xf aliasing)
        ln_fused<<<dim3(M), 256, 0, stream>>>(yb, xf, ln2s + i * D_, ln2b + i * D_, xf, xb);
    }
}

// Round 3
// 4444.670 us; speedup vs baseline: 1.0046x; 1.0046x over previous
//
#include <hip/hip_runtime.h>
#include <hip/hip_bf16.h>

typedef unsigned short u16;

#define B_  4
#define S_  4096
#define D_  1024
#define A_  1024
#define FF_ 4096
#define NB  4
#define LN_EPS 1e-6f

typedef __bf16 bf16x8 __attribute__((ext_vector_type(8)));
typedef float  floatx4 __attribute__((ext_vector_type(4)));

__device__ __forceinline__ float gelu_f(float x) {
    // jax.nn.gelu approximate=True (tanh form)
    float x3 = x * x * x;
    return 0.5f * x * (1.0f + tanhf(0.7978845608028654f * (x + 0.044715f * x3)));
}

__device__ __forceinline__ u16 f2bf(float f) {
    __bf16 h = (__bf16)f;   // RNE convert
    return *(u16*)&h;
}

__device__ __forceinline__ float bf2f(u16 u) {
    unsigned int v = ((unsigned int)u) << 16;
    float f;
    __builtin_memcpy(&f, &v, 4);
    return f;
}

// async global->LDS 16B (direct-to-LDS DMA; dest = wave-uniform base + lane*16)
__device__ __forceinline__ void gload_lds16(const u16* g, u16* l) {
    __builtin_amdgcn_global_load_lds(
        (const __attribute__((address_space(1))) void*)g,
        (__attribute__((address_space(3))) void*)l, 16, 0, 0);
}

// ---------------- zero the KV/Ksum accumulators ------------------------------
__global__ __launch_bounds__(256) void zero_kv(float* __restrict__ p) {
    int idx = (blockIdx.x * 256 + threadIdx.x) * 4;   // 8 blocks -> 8192 floats
    *(float4*)(p + idx) = (float4){0.f, 0.f, 0.f, 0.f};
}

// ---------------- weight transpose + downcast: W[K,N] f32 -> Wt[N,K] bf16 ----
__global__ __launch_bounds__(256) void transpose_w(const float* __restrict__ W,
                                                   u16* __restrict__ Wt,
                                                   int K, int N) {
    __shared__ float tile[32][33];
    int tx = threadIdx.x;         // 0..31
    int ty = threadIdx.y;         // 0..7
    int n0 = blockIdx.x * 32;
    int k0 = blockIdx.y * 32;
#pragma unroll
    for (int r = 0; r < 4; r++) {
        int k = k0 + ty + r * 8;
        tile[ty + r * 8][tx] = W[(size_t)k * N + n0 + tx];
    }
    __syncthreads();
#pragma unroll
    for (int r = 0; r < 4; r++) {
        int n = n0 + ty + r * 8;
        Wt[(size_t)n * K + k0 + tx] = f2bf(tile[tx][ty + r * 8]);
    }
}

// ---------------- bf16 MFMA GEMM: C[M,N] = A[M,K] * Bt[N,K]^T + bias --------
// m97 structure: 128x128 tile, BK=32, global_load_lds width-16 staging,
// unpadded LDS (DMA lane order), 4 waves x (64x64 via 4x4 MFMA 16x16x32).
// MODE: 0 = elu+1, 1 = identity, 2 = gelu(gelu()), 3 = gelu   (all -> bf16)
template <int MODE>
__global__ __launch_bounds__(256) void gemm_bt(const u16* __restrict__ Amat,
                                               const u16* __restrict__ Bt,
                                               const float* __restrict__ bias,
                                               u16* __restrict__ out,
                                               int M, int N, int K) {
    __shared__ u16 As[128 * 32];   // 8 KB, NO pad: global_load_lds lane order
    __shared__ u16 Bs[128 * 32];

    const int t    = threadIdx.x;
    const int m0   = blockIdx.y * 128;
    const int n0   = blockIdx.x * 128;
    const int wave = t >> 6;
    const int lane = t & 63;
    const int wm   = (wave & 1) * 64;
    const int wn   = (wave >> 1) * 64;
    const int lm   = lane & 15;
    const int quad = lane >> 4;

    floatx4 acc[4][4];
#pragma unroll
    for (int i = 0; i < 4; i++)
#pragma unroll
        for (int j = 0; j < 4; j++) acc[i][j] = (floatx4){0.f, 0.f, 0.f, 0.f};

    for (int k0 = 0; k0 < K; k0 += 32) {
        __syncthreads();
        // stage: 512 16B-chunks per tile; chunk c -> LDS byte c*16,
        // global row = c>>2 (32 shorts/row = 4 chunks), col = (c&3)*8 shorts
#pragma unroll
        for (int p = 0; p < 2; p++) {
            int c   = (p * 4 + wave) * 64 + lane;   // lane-contiguous per wave
            int row = c >> 2;
            int col = (c & 3) * 8;
            gload_lds16(Amat + (size_t)(m0 + row) * K + k0 + col, &As[c * 8]);
            gload_lds16(Bt   + (size_t)(n0 + row) * K + k0 + col, &Bs[c * 8]);
        }
        __syncthreads();   // compiler emits s_waitcnt vmcnt(0) before barrier

        bf16x8 af[4], bf[4];
#pragma unroll
        for (int i = 0; i < 4; i++)
            af[i] = *(const bf16x8*)&As[(wm + i * 16 + lm) * 32 + quad * 8];
#pragma unroll
        for (int j = 0; j < 4; j++)
            bf[j] = *(const bf16x8*)&Bs[(wn + j * 16 + lm) * 32 + quad * 8];

#pragma unroll
        for (int i = 0; i < 4; i++)
#pragma unroll
            for (int j = 0; j < 4; j++)
                acc[i][j] = __builtin_amdgcn_mfma_f32_16x16x32_bf16(af[i], bf[j], acc[i][j], 0, 0, 0);
    }

    // epilogue: D row = quad*4 + reg (within 16), col = lane&15
#pragma unroll
    for (int j = 0; j < 4; j++) {
        int col  = n0 + wn + j * 16 + lm;
        float bv = bias[col];
#pragma unroll
        for (int i = 0; i < 4; i++) {
            int rbase = m0 + wm + i * 16 + quad * 4;
#pragma unroll
            for (int r = 0; r < 4; r++) {
                float z = acc[i][j][r] + bv;
                float o;
                if (MODE == 0)      o = (z > 0.f) ? (z + 1.f) : __expf(z);
                else if (MODE == 1) o = z;
                else if (MODE == 2) o = gelu_f(gelu_f(z));
                else                o = gelu_f(z);
                out[(size_t)(rbase + r) * N + col] = f2bf(o);
            }
        }
    }
}

// ---------------- KV / Ksum reduction over S (4 h per thread, ushort4) -------
__global__ __launch_bounds__(256) void kv_reduce(const u16* __restrict__ Kb,
                                                 const u16* __restrict__ vb,
                                                 float* __restrict__ KV,
                                                 float* __restrict__ Ks) {
    int n  = blockIdx.z;
    int h  = threadIdx.x * 4;          // A_ = 1024 = 256 threads * 4
    int s0 = blockIdx.y * 128;
    const u16* kp = Kb + (size_t)n * S_ * A_ + (size_t)s0 * A_ + h;
    const u16* vp = vb + (size_t)n * S_ * A_ + (size_t)s0 * A_ + h;
    float kv0 = 0.f, kv1 = 0.f, kv2 = 0.f, kv3 = 0.f;
    float ks0 = 0.f, ks1 = 0.f, ks2 = 0.f, ks3 = 0.f;
#pragma unroll 4
    for (int s = 0; s < 128; s++) {
        ushort4 k4 = *(const ushort4*)(kp + (size_t)s * A_);
        ushort4 v4 = *(const ushort4*)(vp + (size_t)s * A_);
        float k0 = bf2f(k4.x), k1 = bf2f(k4.y), k2 = bf2f(k4.z), k3 = bf2f(k4.w);
        kv0 += k0 * bf2f(v4.x); kv1 += k1 * bf2f(v4.y);
        kv2 += k2 * bf2f(v4.z); kv3 += k3 * bf2f(v4.w);
        ks0 += k0; ks1 += k1; ks2 += k2; ks3 += k3;
    }
    int base = n * A_ + h;
    atomicAdd(&KV[base + 0], kv0); atomicAdd(&KV[base + 1], kv1);
    atomicAdd(&KV[base + 2], kv2); atomicAdd(&KV[base + 3], kv3);
    atomicAdd(&Ks[base + 0], ks0); atomicAdd(&Ks[base + 1], ks1);
    atomicAdd(&Ks[base + 2], ks2); atomicAdd(&Ks[base + 3], ks3);
}

// ---------------- elementwise linear-attention output ------------------------
__global__ __launch_bounds__(256) void linattn_ew(const u16* __restrict__ Qb,
                                                  const float* __restrict__ KV,
                                                  const float* __restrict__ Ks,
                                                  u16* __restrict__ vout) {
    size_t idx = ((size_t)blockIdx.x * 256 + threadIdx.x) * 4;
    int n = (int)(idx >> 22);          // S_*A_ = 2^22
    int h = (int)(idx & (A_ - 1));
    ushort4 q4 = *(const ushort4*)(Qb + idx);
    int base = n * A_ + h;
    float q0 = bf2f(q4.x), q1 = bf2f(q4.y), q2 = bf2f(q4.z), q3 = bf2f(q4.w);
    float o0 = q0 * KV[base + 0] / (q0 * Ks[base + 0] + 1e-6f);
    float o1 = q1 * KV[base + 1] / (q1 * Ks[base + 1] + 1e-6f);
    float o2 = q2 * KV[base + 2] / (q2 * Ks[base + 2] + 1e-6f);
    float o3 = q3 * KV[base + 3] / (q3 * Ks[base + 3] + 1e-6f);
    ushort4 o;
    o.x = f2bf(o0); o.y = f2bf(o1); o.z = f2bf(o2); o.w = f2bf(o3);
    *(ushort4*)(vout + idx) = o;
}

// ---------------- x init: f32 copy (residual) + bf16 cast --------------------
__global__ __launch_bounds__(256) void convert_x(const float* __restrict__ x,
                                                 float* __restrict__ xf,
                                                 u16* __restrict__ xb) {
    size_t idx = ((size_t)blockIdx.x * 256 + threadIdx.x) * 4;
    float4 v = *(const float4*)(x + idx);
    *(float4*)(xf + idx) = v;
    ushort4 o;
    o.x = f2bf(v.x); o.y = f2bf(v.y); o.z = f2bf(v.z); o.w = f2bf(v.w);
    *(ushort4*)(xb + idx) = o;
}

// ---------------- fused residual + LayerNorm (y in bf16, residual fp32) ------
__global__ __launch_bounds__(256) void ln_fused(const u16* __restrict__ y,
                                                const float* __restrict__ res,
                                                const float* __restrict__ sc,
                                                const float* __restrict__ bs,
                                                float* __restrict__ xf,
                                                u16* __restrict__ xb) {
    __shared__ float red[256];
    int row = blockIdx.x;
    int t   = threadIdx.x;
    const u16* yp   = y + (size_t)row * D_;
    const float* rp = res + (size_t)row * D_;
    float v[4];
    float lsum = 0.f;
#pragma unroll
    for (int i = 0; i < 4; i++) {
        int j = t + i * 256;
        v[i] = bf2f(yp[j]) + rp[j];
        lsum += v[i];
    }
    red[t] = lsum;
    __syncthreads();
    for (int s = 128; s > 0; s >>= 1) {
        if (t < s) red[t] += red[t + s];
        __syncthreads();
    }
    float mean = red[0] * (1.0f / D_);
    __syncthreads();
    float lvar = 0.f;
#pragma unroll
    for (int i = 0; i < 4; i++) {
        float d = v[i] - mean;
        lvar += d * d;
    }
    red[t] = lvar;
    __syncthreads();
    for (int s = 128; s > 0; s >>= 1) {
        if (t < s) red[t] += red[t + s];
        __syncthreads();
    }
    float rstd = rsqrtf(red[0] * (1.0f / D_) + LN_EPS);
#pragma unroll
    for (int i = 0; i < 4; i++) {
        int j = t + i * 256;
        float o = (v[i] - mean) * rstd * sc[j] + bs[j];
        xf[(size_t)row * D_ + j] = o;
        xb[(size_t)row * D_ + j] = f2bf(o);
    }
}

extern "C" void kernel_launch(void* const* d_in, const int* in_sizes, int n_in,
                              void* d_out, int out_size, void* d_ws, size_t ws_size,
                              hipStream_t stream) {
    const float* x_in = (const float*)d_in[0];
    const float* Wq   = (const float*)d_in[1];
    const float* bq   = (const float*)d_in[2];
    const float* Wk   = (const float*)d_in[3];
    const float* bk   = (const float*)d_in[4];
    const float* Wv   = (const float*)d_in[5];
    const float* bv   = (const float*)d_in[6];
    const float* Wo   = (const float*)d_in[7];
    const float* bo   = (const float*)d_in[8];
    const float* ln1s = (const float*)d_in[9];
    const float* ln1b = (const float*)d_in[10];
    const float* W1   = (const float*)d_in[11];
    const float* b1   = (const float*)d_in[12];
    const float* W2   = (const float*)d_in[13];
    const float* b2   = (const float*)d_in[14];
    const float* ln2s = (const float*)d_in[15];
    const float* ln2b = (const float*)d_in[16];

    const size_t MB = 1024 * 1024;
    char* ws = (char*)d_ws;
    // Workspace layout: 176 MB total. d_out doubles as the fp32 residual.
    float* xf  = (float*)d_out;              // 64 MB  fp32 residual / final out
    u16*   xb  = (u16*)(ws);                 // 32 MB  bf16 x (GEMM A)
    u16*   yb  = (u16*)(ws + 32 * MB);       // 32 MB  bf16 GEMM out: v / a / f
    u16*   Qb  = (u16*)(ws + 64 * MB);       // 32 MB  bf16 Q
    u16*   Kb  = (u16*)(ws + 96 * MB);       // 32 MB  bf16 K, then Vattn
    u16*   hcb = (u16*)(ws + 128 * MB);      // 32 MB  bf16 FF hidden (4096-row chunk)
    u16*   Wt1 = (u16*)(ws + 160 * MB);      // 8 MB   bf16 transposed weight
    u16*   Wt2 = (u16*)(ws + 168 * MB);      // 8 MB   bf16 transposed weight (W2)
    float* kvb = (float*)(ws + 128 * MB);    // 32 KB  KV+Ksum (overlays hcb; disjoint in time)
    float* KV  = kvb;
    float* Ks  = kvb + B_ * A_;

    const int M = B_ * S_;   // 16384
    const int MC = 4096;     // FF row chunk

    convert_x<<<dim3(M * D_ / 1024), 256, 0, stream>>>(x_in, xf, xb);

    for (int i = 0; i < NB; i++) {
        const float* Wq_i = Wq + (size_t)i * D_ * A_;
        const float* Wk_i = Wk + (size_t)i * D_ * A_;
        const float* Wv_i = Wv + (size_t)i * D_ * A_;
        const float* Wo_i = Wo + (size_t)i * A_ * D_;
        const float* W1_i = W1 + (size_t)i * D_ * FF_;
        const float* W2_i = W2 + (size_t)i * FF_ * D_;

        // Q = elu(x@Wq + bq) + 1
        transpose_w<<<dim3(A_ / 32, D_ / 32), dim3(32, 8), 0, stream>>>(Wq_i, Wt1, D_, A_);
        gemm_bt<0><<<dim3(A_ / 128, M / 128), 256, 0, stream>>>(xb, Wt1, bq + i * A_, Qb, M, A_, D_);
        // K = elu(x@Wk + bk) + 1
        transpose_w<<<dim3(A_ / 32, D_ / 32), dim3(32, 8), 0, stream>>>(Wk_i, Wt1, D_, A_);
        gemm_bt<0><<<dim3(A_ / 128, M / 128), 256, 0, stream>>>(xb, Wt1, bk + i * A_, Kb, M, A_, D_);
        // v = x@Wv + bv
        transpose_w<<<dim3(A_ / 32, D_ / 32), dim3(32, 8), 0, stream>>>(Wv_i, Wt1, D_, A_);
        gemm_bt<1><<<dim3(A_ / 128, M / 128), 256, 0, stream>>>(xb, Wt1, bv + i * A_, yb, M, A_, D_);

        // KV[n,h] = sum_s K*v ; Ksum[n,h] = sum_s K
        zero_kv<<<dim3(8), 256, 0, stream>>>(kvb);
        kv_reduce<<<dim3(1, S_ / 128, B_), 256, 0, stream>>>(Kb, yb, KV, Ks);

        // Vattn = Q*KV / (Q*Ksum + 1e-6)  (overwrites Kb)
        linattn_ew<<<dim3(M * A_ / 1024), 256, 0, stream>>>(Qb, KV, Ks, Kb);

        // a = gelu(gelu(Vattn@Wo + bo))
        transpose_w<<<dim3(D_ / 32, A_ / 32), dim3(32, 8), 0, stream>>>(Wo_i, Wt1, A_, D_);
        gemm_bt<2><<<dim3(D_ / 128, M / 128), 256, 0, stream>>>(Kb, Wt1, bo + i * D_, yb, M, D_, A_);

        // x = LN(a + residual)
        ln_fused<<<dim3(M), 256, 0, stream>>>(yb, xf, ln1s + i * D_, ln1b + i * D_, xf, xb);

        // FF, chunked over rows to keep the hidden buffer at 32 MB
        transpose_w<<<dim3(FF_ / 32, D_ / 32), dim3(32, 8), 0, stream>>>(W1_i, Wt1, D_, FF_);
        transpose_w<<<dim3(D_ / 32, FF_ / 32), dim3(32, 8), 0, stream>>>(W2_i, Wt2, FF_, D_);
        for (int c = 0; c < M / MC; c++) {
            const u16* xbc = xb + (size_t)c * MC * D_;
            u16*       ybc = yb + (size_t)c * MC * D_;
            // h = gelu(x@W1 + b1)
            gemm_bt<3><<<dim3(FF_ / 128, MC / 128), 256, 0, stream>>>(xbc, Wt1, b1 + i * FF_, hcb, MC, FF_, D_);
            // f = gelu(h@W2 + b2)
            gemm_bt<3><<<dim3(D_ / 128, MC / 128), 256, 0, stream>>>(hcb, Wt2, b2 + i * D_, ybc, MC, D_, FF_);
        }

        // x = LN(f + residual)  (final block writes d_out via xf aliasing)
        ln_fused<<<dim3(M), 256, 0, stream>>>(yb, xf, ln2s + i * D_, ln2b + i * D_, xf, xb);
    }
}

// Round 4
// 3986.646 us; speedup vs baseline: 1.1200x; 1.1149x over previous
//
#include <hip/hip_runtime.h>
#include <hip/hip_bf16.h>

typedef unsigned short u16;

#define B_  4
#define S_  4096
#define D_  1024
#define A_  1024
#define FF_ 4096
#define NB  4
#define LN_EPS 1e-6f

typedef __bf16 bf16x8 __attribute__((ext_vector_type(8)));
typedef float  floatx4 __attribute__((ext_vector_type(4)));

__device__ __forceinline__ float gelu_f(float x) {
    // jax.nn.gelu approximate=True: 0.5x(1+tanh(u)) == x * sigmoid(2u)
    float u = 0.7978845608028654f * (x + 0.044715f * x * x * x);
    return x / (1.0f + __expf(-2.0f * u));
}

__device__ __forceinline__ u16 f2bf(float f) {
    __bf16 h = (__bf16)f;   // RNE convert
    return *(u16*)&h;
}

__device__ __forceinline__ float bf2f(u16 u) {
    unsigned int v = ((unsigned int)u) << 16;
    float f;
    __builtin_memcpy(&f, &v, 4);
    return f;
}

// async global->LDS 16B (direct-to-LDS DMA; dest = wave-uniform base + lane*16)
__device__ __forceinline__ void gload_lds16(const u16* g, u16* l) {
    __builtin_amdgcn_global_load_lds(
        (const __attribute__((address_space(1))) void*)g,
        (__attribute__((address_space(3))) void*)l, 16, 0, 0);
}

// ---------------- zero the KV/Ksum accumulators ------------------------------
__global__ __launch_bounds__(256) void zero_kv(float* __restrict__ p) {
    int idx = (blockIdx.x * 256 + threadIdx.x) * 4;   // 8 blocks -> 8192 floats
    *(float4*)(p + idx) = (float4){0.f, 0.f, 0.f, 0.f};
}

// ---------------- weight transpose + downcast: W[K,N] f32 -> Wt[N,K] bf16 ----
__global__ __launch_bounds__(256) void transpose_w(const float* __restrict__ W,
                                                   u16* __restrict__ Wt,
                                                   int K, int N) {
    __shared__ float tile[32][33];
    int tx = threadIdx.x;         // 0..31
    int ty = threadIdx.y;         // 0..7
    int n0 = blockIdx.x * 32;
    int k0 = blockIdx.y * 32;
#pragma unroll
    for (int r = 0; r < 4; r++) {
        int k = k0 + ty + r * 8;
        tile[ty + r * 8][tx] = W[(size_t)k * N + n0 + tx];
    }
    __syncthreads();
#pragma unroll
    for (int r = 0; r < 4; r++) {
        int n = n0 + ty + r * 8;
        Wt[(size_t)n * K + k0 + tx] = f2bf(tile[tx][ty + r * 8]);
    }
}

// ---------------- bf16 MFMA GEMM: C[M,N] = A[M,K] * Bt[N,K]^T + bias --------
// m97 structure + XCD-aware swizzle: 1D grid; xcd = bid&7 owns a contiguous
// (gx/sx) x (gy/(8/sx)) region of the tile grid so its private L2 sees a
// small working set instead of the whole A matrix.
// MODE: 0 = elu+1, 1 = identity, 2 = gelu(gelu()), 3 = gelu   (all -> bf16)
template <int MODE>
__global__ __launch_bounds__(256) void gemm_bt(const u16* __restrict__ Amat,
                                               const u16* __restrict__ Bt,
                                               const float* __restrict__ bias,
                                               u16* __restrict__ out,
                                               int M, int N, int K,
                                               int gx, int gy, int sx) {
    __shared__ u16 As[128 * 32];   // 8 KB, NO pad: global_load_lds lane order
    __shared__ u16 Bs[128 * 32];

    // --- XCD swizzle: bid -> (bx, by) ---
    int bid = blockIdx.x;
    int xcd = bid & 7;
    int idx = bid >> 3;
    int sy  = 8 / sx;
    int w   = gx / sx;
    int h   = gy / sy;
    int bx  = (xcd % sx) * w + idx % w;
    int by  = (xcd / sx) * h + idx / w;

    const int t    = threadIdx.x;
    const int m0   = by * 128;
    const int n0   = bx * 128;
    const int wave = t >> 6;
    const int lane = t & 63;
    const int wm   = (wave & 1) * 64;
    const int wn   = (wave >> 1) * 64;
    const int lm   = lane & 15;
    const int quad = lane >> 4;

    floatx4 acc[4][4];
#pragma unroll
    for (int i = 0; i < 4; i++)
#pragma unroll
        for (int j = 0; j < 4; j++) acc[i][j] = (floatx4){0.f, 0.f, 0.f, 0.f};

    for (int k0 = 0; k0 < K; k0 += 32) {
        __syncthreads();
        // stage: 512 16B-chunks per tile; chunk c -> LDS byte c*16,
        // global row = c>>2 (32 shorts/row = 4 chunks), col = (c&3)*8 shorts
#pragma unroll
        for (int p = 0; p < 2; p++) {
            int c   = (p * 4 + wave) * 64 + lane;   // lane-contiguous per wave
            int row = c >> 2;
            int col = (c & 3) * 8;
            gload_lds16(Amat + (size_t)(m0 + row) * K + k0 + col, &As[c * 8]);
            gload_lds16(Bt   + (size_t)(n0 + row) * K + k0 + col, &Bs[c * 8]);
        }
        __syncthreads();

        bf16x8 af[4], bf[4];
#pragma unroll
        for (int i = 0; i < 4; i++)
            af[i] = *(const bf16x8*)&As[(wm + i * 16 + lm) * 32 + quad * 8];
#pragma unroll
        for (int j = 0; j < 4; j++)
            bf[j] = *(const bf16x8*)&Bs[(wn + j * 16 + lm) * 32 + quad * 8];

#pragma unroll
        for (int i = 0; i < 4; i++)
#pragma unroll
            for (int j = 0; j < 4; j++)
                acc[i][j] = __builtin_amdgcn_mfma_f32_16x16x32_bf16(af[i], bf[j], acc[i][j], 0, 0, 0);
    }

    // epilogue: D row = quad*4 + reg (within 16), col = lane&15
#pragma unroll
    for (int j = 0; j < 4; j++) {
        int col  = n0 + wn + j * 16 + lm;
        float bv = bias[col];
#pragma unroll
        for (int i = 0; i < 4; i++) {
            int rbase = m0 + wm + i * 16 + quad * 4;
#pragma unroll
            for (int r = 0; r < 4; r++) {
                float z = acc[i][j][r] + bv;
                float o;
                if (MODE == 0)      o = (z > 0.f) ? (z + 1.f) : __expf(z);
                else if (MODE == 1) o = z;
                else if (MODE == 2) o = gelu_f(gelu_f(z));
                else                o = gelu_f(z);
                out[(size_t)(rbase + r) * N + col] = f2bf(o);
            }
        }
    }
}

// ---------------- KV / Ksum reduction over S (4 h per thread, ushort4) -------
__global__ __launch_bounds__(256) void kv_reduce(const u16* __restrict__ Kb,
                                                 const u16* __restrict__ vb,
                                                 float* __restrict__ KV,
                                                 float* __restrict__ Ks) {
    int n  = blockIdx.z;
    int h  = threadIdx.x * 4;          // A_ = 1024 = 256 threads * 4
    int s0 = blockIdx.y * 128;
    const u16* kp = Kb + (size_t)n * S_ * A_ + (size_t)s0 * A_ + h;
    const u16* vp = vb + (size_t)n * S_ * A_ + (size_t)s0 * A_ + h;
    float kv0 = 0.f, kv1 = 0.f, kv2 = 0.f, kv3 = 0.f;
    float ks0 = 0.f, ks1 = 0.f, ks2 = 0.f, ks3 = 0.f;
#pragma unroll 4
    for (int s = 0; s < 128; s++) {
        ushort4 k4 = *(const ushort4*)(kp + (size_t)s * A_);
        ushort4 v4 = *(const ushort4*)(vp + (size_t)s * A_);
        float k0 = bf2f(k4.x), k1 = bf2f(k4.y), k2 = bf2f(k4.z), k3 = bf2f(k4.w);
        kv0 += k0 * bf2f(v4.x); kv1 += k1 * bf2f(v4.y);
        kv2 += k2 * bf2f(v4.z); kv3 += k3 * bf2f(v4.w);
        ks0 += k0; ks1 += k1; ks2 += k2; ks3 += k3;
    }
    int base = n * A_ + h;
    atomicAdd(&KV[base + 0], kv0); atomicAdd(&KV[base + 1], kv1);
    atomicAdd(&KV[base + 2], kv2); atomicAdd(&KV[base + 3], kv3);
    atomicAdd(&Ks[base + 0], ks0); atomicAdd(&Ks[base + 1], ks1);
    atomicAdd(&Ks[base + 2], ks2); atomicAdd(&Ks[base + 3], ks3);
}

// ---------------- elementwise linear-attention output ------------------------
__global__ __launch_bounds__(256) void linattn_ew(const u16* __restrict__ Qb,
                                                  const float* __restrict__ KV,
                                                  const float* __restrict__ Ks,
                                                  u16* __restrict__ vout) {
    size_t idx = ((size_t)blockIdx.x * 256 + threadIdx.x) * 4;
    int n = (int)(idx >> 22);          // S_*A_ = 2^22
    int h = (int)(idx & (A_ - 1));
    ushort4 q4 = *(const ushort4*)(Qb + idx);
    int base = n * A_ + h;
    float q0 = bf2f(q4.x), q1 = bf2f(q4.y), q2 = bf2f(q4.z), q3 = bf2f(q4.w);
    float o0 = q0 * KV[base + 0] / (q0 * Ks[base + 0] + 1e-6f);
    float o1 = q1 * KV[base + 1] / (q1 * Ks[base + 1] + 1e-6f);
    float o2 = q2 * KV[base + 2] / (q2 * Ks[base + 2] + 1e-6f);
    float o3 = q3 * KV[base + 3] / (q3 * Ks[base + 3] + 1e-6f);
    ushort4 o;
    o.x = f2bf(o0); o.y = f2bf(o1); o.z = f2bf(o2); o.w = f2bf(o3);
    *(ushort4*)(vout + idx) = o;
}

// ---------------- x init: f32 copy (residual) + bf16 cast --------------------
__global__ __launch_bounds__(256) void convert_x(const float* __restrict__ x,
                                                 float* __restrict__ xf,
                                                 u16* __restrict__ xb) {
    size_t idx = ((size_t)blockIdx.x * 256 + threadIdx.x) * 4;
    float4 v = *(const float4*)(x + idx);
    *(float4*)(xf + idx) = v;
    ushort4 o;
    o.x = f2bf(v.x); o.y = f2bf(v.y); o.z = f2bf(v.z); o.w = f2bf(v.w);
    *(ushort4*)(xb + idx) = o;
}

// ---------------- fused residual + LayerNorm (y in bf16, residual fp32) ------
__global__ __launch_bounds__(256) void ln_fused(const u16* __restrict__ y,
                                                const float* __restrict__ res,
                                                const float* __restrict__ sc,
                                                const float* __restrict__ bs,
                                                float* __restrict__ xf,
                                                u16* __restrict__ xb) {
    __shared__ float red[256];
    int row = blockIdx.x;
    int t   = threadIdx.x;
    const u16* yp   = y + (size_t)row * D_;
    const float* rp = res + (size_t)row * D_;
    float v[4];
    float lsum = 0.f;
#pragma unroll
    for (int i = 0; i < 4; i++) {
        int j = t + i * 256;
        v[i] = bf2f(yp[j]) + rp[j];
        lsum += v[i];
    }
    red[t] = lsum;
    __syncthreads();
    for (int s = 128; s > 0; s >>= 1) {
        if (t < s) red[t] += red[t + s];
        __syncthreads();
    }
    float mean = red[0] * (1.0f / D_);
    __syncthreads();
    float lvar = 0.f;
#pragma unroll
    for (int i = 0; i < 4; i++) {
        float d = v[i] - mean;
        lvar += d * d;
    }
    red[t] = lvar;
    __syncthreads();
    for (int s = 128; s > 0; s >>= 1) {
        if (t < s) red[t] += red[t + s];
        __syncthreads();
    }
    float rstd = rsqrtf(red[0] * (1.0f / D_) + LN_EPS);
#pragma unroll
    for (int i = 0; i < 4; i++) {
        int j = t + i * 256;
        float o = (v[i] - mean) * rstd * sc[j] + bs[j];
        xf[(size_t)row * D_ + j] = o;
        xb[(size_t)row * D_ + j] = f2bf(o);
    }
}

extern "C" void kernel_launch(void* const* d_in, const int* in_sizes, int n_in,
                              void* d_out, int out_size, void* d_ws, size_t ws_size,
                              hipStream_t stream) {
    const float* x_in = (const float*)d_in[0];
    const float* Wq   = (const float*)d_in[1];
    const float* bq   = (const float*)d_in[2];
    const float* Wk   = (const float*)d_in[3];
    const float* bk   = (const float*)d_in[4];
    const float* Wv   = (const float*)d_in[5];
    const float* bv   = (const float*)d_in[6];
    const float* Wo   = (const float*)d_in[7];
    const float* bo   = (const float*)d_in[8];
    const float* ln1s = (const float*)d_in[9];
    const float* ln1b = (const float*)d_in[10];
    const float* W1   = (const float*)d_in[11];
    const float* b1   = (const float*)d_in[12];
    const float* W2   = (const float*)d_in[13];
    const float* b2   = (const float*)d_in[14];
    const float* ln2s = (const float*)d_in[15];
    const float* ln2b = (const float*)d_in[16];

    const size_t MB = 1024 * 1024;
    char* ws = (char*)d_ws;
    // Workspace layout: 176 MB total. d_out doubles as the fp32 residual.
    float* xf  = (float*)d_out;              // 64 MB  fp32 residual / final out
    u16*   xb  = (u16*)(ws);                 // 32 MB  bf16 x (GEMM A)
    u16*   yb  = (u16*)(ws + 32 * MB);       // 32 MB  bf16 GEMM out: v / a / f
    u16*   Qb  = (u16*)(ws + 64 * MB);       // 32 MB  bf16 Q
    u16*   Kb  = (u16*)(ws + 96 * MB);       // 32 MB  bf16 K, then Vattn
    u16*   hcb = (u16*)(ws + 128 * MB);      // 32 MB  bf16 FF hidden (4096-row chunk)
    u16*   Wt1 = (u16*)(ws + 160 * MB);      // 8 MB   bf16 transposed weight
    u16*   Wt2 = (u16*)(ws + 168 * MB);      // 8 MB   bf16 transposed weight (W2)
    float* kvb = (float*)(ws + 128 * MB);    // 32 KB  KV+Ksum (overlays hcb; disjoint in time)
    float* KV  = kvb;
    float* Ks  = kvb + B_ * A_;

    const int M = B_ * S_;   // 16384
    const int MC = 4096;     // FF row chunk

    convert_x<<<dim3(M * D_ / 1024), 256, 0, stream>>>(x_in, xf, xb);

    for (int i = 0; i < NB; i++) {
        const float* Wq_i = Wq + (size_t)i * D_ * A_;
        const float* Wk_i = Wk + (size_t)i * D_ * A_;
        const float* Wv_i = Wv + (size_t)i * D_ * A_;
        const float* Wo_i = Wo + (size_t)i * A_ * D_;
        const float* W1_i = W1 + (size_t)i * D_ * FF_;
        const float* W2_i = W2 + (size_t)i * FF_ * D_;

        // grids: (gx=N/128, gy=M/128) flattened 1D with XCD swizzle.
        // N=1024 gemms: gx=8, sx=1 -> each XCD a 16-row y-band (A 4MB + B 2MB).
        // Q = elu(x@Wq + bq) + 1
        transpose_w<<<dim3(A_ / 32, D_ / 32), dim3(32, 8), 0, stream>>>(Wq_i, Wt1, D_, A_);
        gemm_bt<0><<<dim3(8 * 128), 256, 0, stream>>>(xb, Wt1, bq + i * A_, Qb, M, A_, D_, 8, 128, 1);
        // K = elu(x@Wk + bk) + 1
        transpose_w<<<dim3(A_ / 32, D_ / 32), dim3(32, 8), 0, stream>>>(Wk_i, Wt1, D_, A_);
        gemm_bt<0><<<dim3(8 * 128), 256, 0, stream>>>(xb, Wt1, bk + i * A_, Kb, M, A_, D_, 8, 128, 1);
        // v = x@Wv + bv
        transpose_w<<<dim3(A_ / 32, D_ / 32), dim3(32, 8), 0, stream>>>(Wv_i, Wt1, D_, A_);
        gemm_bt<1><<<dim3(8 * 128), 256, 0, stream>>>(xb, Wt1, bv + i * A_, yb, M, A_, D_, 8, 128, 1);

        // KV[n,h] = sum_s K*v ; Ksum[n,h] = sum_s K
        zero_kv<<<dim3(8), 256, 0, stream>>>(kvb);
        kv_reduce<<<dim3(1, S_ / 128, B_), 256, 0, stream>>>(Kb, yb, KV, Ks);

        // Vattn = Q*KV / (Q*Ksum + 1e-6)  (overwrites Kb)
        linattn_ew<<<dim3(M * A_ / 1024), 256, 0, stream>>>(Qb, KV, Ks, Kb);

        // a = gelu(gelu(Vattn@Wo + bo))
        transpose_w<<<dim3(D_ / 32, A_ / 32), dim3(32, 8), 0, stream>>>(Wo_i, Wt1, A_, D_);
        gemm_bt<2><<<dim3(8 * 128), 256, 0, stream>>>(Kb, Wt1, bo + i * D_, yb, M, D_, A_, 8, 128, 1);

        // x = LN(a + residual)
        ln_fused<<<dim3(M), 256, 0, stream>>>(yb, xf, ln1s + i * D_, ln1b + i * D_, xf, xb);

        // FF, chunked over rows to keep the hidden buffer at 32 MB
        transpose_w<<<dim3(FF_ / 32, D_ / 32), dim3(32, 8), 0, stream>>>(W1_i, Wt1, D_, FF_);
        transpose_w<<<dim3(D_ / 32, FF_ / 32), dim3(32, 8), 0, stream>>>(W2_i, Wt2, FF_, D_);
        for (int c = 0; c < M / MC; c++) {
            const u16* xbc = xb + (size_t)c * MC * D_;
            u16*       ybc = yb + (size_t)c * MC * D_;
            // h = gelu(x@W1 + b1): grid 32x32, sx=2 -> 16x8 regions per XCD
            gemm_bt<3><<<dim3(32 * 32), 256, 0, stream>>>(xbc, Wt1, b1 + i * FF_, hcb, MC, FF_, D_, 32, 32, 2);
            // f = gelu(h@W2 + b2): grid 8x32, sx=1 -> 4-row y-bands per XCD
            gemm_bt<3><<<dim3(8 * 32), 256, 0, stream>>>(hcb, Wt2, b2 + i * D_, ybc, MC, D_, FF_, 8, 32, 1);
        }

        // x = LN(f + residual)  (final block writes d_out via xf aliasing)
        ln_fused<<<dim3(M), 256, 0, stream>>>(yb, xf, ln2s + i * D_, ln2b + i * D_, xf, xb);
    }
}